// Round 10
// baseline (335.295 us; speedup 1.0000x reference)
//
#include <hip/hip_runtime.h>
#include <hip/hip_bf16.h>
#include <math.h>

// B=4, T=2048, C=1024, H=16, D=64. All dims divide tiles exactly.
typedef __bf16 bf16;
typedef __bf16 bf16x8 __attribute__((ext_vector_type(8)));
typedef __bf16 bf16x4 __attribute__((ext_vector_type(4)));
typedef float  f32x4  __attribute__((ext_vector_type(4)));

// async 16B/lane global->LDS. lds base must be wave-uniform; HW adds lane*16.
__device__ __forceinline__ void gld_lds16(const bf16* g, bf16* l) {
    void* gv = (void*)g;  // drop const
    __builtin_amdgcn_global_load_lds(
        (__attribute__((address_space(1))) void*)gv,
        (__attribute__((address_space(3))) void*)l, 16, 0, 0);
}

// ---------------- fp32 -> bf16 elementwise cast ----------------
__global__ void k_cvt_bf16(const float* __restrict__ in, bf16* __restrict__ out, int n4) {
    int i = blockIdx.x * blockDim.x + threadIdx.x;
    if (i < n4) {
        float4 v = ((const float4*)in)[i];
        bf16x4 o;
        o[0] = (bf16)v.x; o[1] = (bf16)v.y; o[2] = (bf16)v.z; o[3] = (bf16)v.w;
        ((bf16x4*)out)[i] = o;
    }
}

// ---------------- fp32 [R][C] -> bf16 [C][R] transpose+cast ----------------
// grid (C/64, R/64), block 256
__global__ void k_transpose_cvt(const float* __restrict__ in, bf16* __restrict__ out,
                                int R, int C) {
    __shared__ float tile[64][68];
    int c0 = blockIdx.x * 64, r0 = blockIdx.y * 64;
    int tid = threadIdx.x;
#pragma unroll
    for (int i = 0; i < 4; ++i) {            // 1024 float4 chunks
        int chunk = tid + i * 256;
        int r = chunk >> 4, c4 = (chunk & 15) * 4;
        float4 v = *(const float4*)(in + (size_t)(r0 + r) * C + c0 + c4);
        tile[r][c4 + 0] = v.x; tile[r][c4 + 1] = v.y;
        tile[r][c4 + 2] = v.z; tile[r][c4 + 3] = v.w;
    }
    __syncthreads();
#pragma unroll
    for (int i = 0; i < 2; ++i) {            // 512 chunks of 8 bf16
        int chunk = tid + i * 256;
        int c = chunk >> 3, k8 = (chunk & 7) * 8;
        bf16x8 v;
#pragma unroll
        for (int j = 0; j < 8; ++j) v[j] = (bf16)tile[k8 + j][c];
        *(bf16x8*)(out + (size_t)(c0 + c) * R + r0 + k8) = v;
    }
}

// ---------------- V slice of qkv -> vt[(bh*64+d)*2048 + t] ----------------
// grid (T/64, B*H), block 256
__global__ void k_transpose_v(const bf16* __restrict__ qkv, bf16* __restrict__ vt) {
    __shared__ bf16 tile[64][72];
    int bh = blockIdx.y, b = bh >> 4, h = bh & 15;
    int t0 = blockIdx.x * 64;
    int tid = threadIdx.x;
    const bf16* src = qkv + (size_t)(b * 2048 + t0) * 3072 + 2048 + h * 64;
#pragma unroll
    for (int i = 0; i < 2; ++i) {
        int chunk = tid + i * 256;
        int t = chunk >> 3, d8 = (chunk & 7) * 8;
        bf16x8 v = *(const bf16x8*)(src + (size_t)t * 3072 + d8);
#pragma unroll
        for (int j = 0; j < 8; ++j) tile[t][d8 + j] = v[j];
    }
    __syncthreads();
#pragma unroll
    for (int i = 0; i < 2; ++i) {
        int chunk = tid + i * 256;
        int d = chunk >> 3, t8 = (chunk & 7) * 8;
        bf16x8 v;
#pragma unroll
        for (int j = 0; j < 8; ++j) v[j] = tile[t8 + j][d];
        *(bf16x8*)(vt + ((size_t)bh * 64 + d) * 2048 + t0 + t8) = v;
    }
}

// ---------------- GEMM: C[M][N] = A[M][K] * Bt[N][K]^T + bias ----------------
// 128x128 block tile, 4 waves (2x2) of 64x64, BK=64 kf-split LDS [2][128][32]
// (bank-uniform), global_load_lds width=16 staging, mfma 16x16x32 bf16.
// (Round-8 lesson: explicit double-buffer 2-phase was neutral-to-negative —
// Common-mistake #5; implicit 2-block/CU overlap already covers the latency.)
template <bool OUT_BF16>
__global__ __launch_bounds__(256, 2) void k_gemm(
    const bf16* __restrict__ A, const bf16* __restrict__ Bt,
    const float* __restrict__ bias, void* __restrict__ Cout,
    int M, int N, int K) {
    __shared__ __align__(16) bf16 lA[2][4096];
    __shared__ __align__(16) bf16 lB[2][4096];
    int tid = threadIdx.x;
    int wid = tid >> 6, lane = tid & 63;
    int quad = lane >> 4, l16 = lane & 15;
    int bm = blockIdx.y * 128, bn = blockIdx.x * 128;
    int wm = (wid >> 1) * 64, wn = (wid & 1) * 64;

    f32x4 zero = {0.f, 0.f, 0.f, 0.f};
    f32x4 acc[4][4];
#pragma unroll
    for (int i = 0; i < 4; ++i)
#pragma unroll
        for (int j = 0; j < 4; ++j) acc[i][j] = zero;

    for (int k0 = 0; k0 < K; k0 += 64) {
        __syncthreads();
#pragma unroll
        for (int i = 0; i < 4; ++i) {
            int j = (wid * 4 + i) * 64 + lane;          // 0..1023
            int kf = j >> 9, row = (j & 511) >> 2, c8 = (j & 3) * 8;
            gld_lds16(A  + (size_t)(bm + row) * K + k0 + kf * 32 + c8, &lA[0][0] + (wid * 4 + i) * 512);
            gld_lds16(Bt + (size_t)(bn + row) * K + k0 + kf * 32 + c8, &lB[0][0] + (wid * 4 + i) * 512);
        }
        __syncthreads();
#pragma unroll
        for (int kk = 0; kk < 2; ++kk) {
            bf16x8 af[4], bg[4];
#pragma unroll
            for (int i = 0; i < 4; ++i) {
                af[i] = *(const bf16x8*)(&lA[kk][(wm + i * 16 + l16) * 32 + quad * 8]);
                bg[i] = *(const bf16x8*)(&lB[kk][(wn + i * 16 + l16) * 32 + quad * 8]);
            }
#pragma unroll
            for (int i = 0; i < 4; ++i)
#pragma unroll
                for (int j = 0; j < 4; ++j)
                    acc[i][j] = __builtin_amdgcn_mfma_f32_16x16x32_bf16(af[i], bg[j], acc[i][j], 0, 0, 0);
        }
    }
#pragma unroll
    for (int i = 0; i < 4; ++i) {
#pragma unroll
        for (int j = 0; j < 4; ++j) {
            int col = bn + wn + j * 16 + l16;
            float bv = bias ? bias[col] : 0.f;
#pragma unroll
            for (int r = 0; r < 4; ++r) {
                int row = bm + wm + i * 16 + quad * 4 + r;
                float v = acc[i][j][r] + bv;
                if (OUT_BF16) ((bf16*)Cout)[(size_t)row * N + col] = (bf16)v;
                else          ((float*)Cout)[(size_t)row * N + col] = v;
            }
        }
    }
}

// ---------------- flash attention (v13: v11 + V direct-from-L2) --------------
// Base = v11 (79.8us). Delta: V is NOT staged through LDS. V fragment loads
// are fully 64B-line-efficient straight from global (vt is [d][t], each
// vb[dn] load covers 16 rows x 64B aligned), vt per bh = 256KB and XCD-local
// (bh->XCD spread) => L2-resident. Loads are issued ~300+cy before use
// (vb[kf=0] right after QK, vb[kf=1] before kf=0's PV) so L2 latency hides
// behind exp + P-writes — unlike v10, which demand-loaded K AND V with no
// pipeline and regressed. Removes: stageV, vmcnt(2) stall, 16KB LDS write +
// 8KB read per block-tile. LDS 33.8->25.6KB. Also: skip the kf=1 half
// entirely on even-rb diagonal tiles (khi) — was zero-P writes + 10 dead
// MFMAs. Kept: K double-buffer + XOR swizzle both-sides, lP kf-split
// [32][36], MINIT C-operand init, exp2 domain, MFMA-ones rowsum,
// heavy-qb-first static mapping (work-stealing breaks L2 locality: r7).
__global__ __launch_bounds__(256, 4) void k_attn(
    const bf16* __restrict__ qkv,   // [B*T][3072]
    const bf16* __restrict__ vt,    // [(bh*64+d)*2048 + t]
    bf16* __restrict__ y) {         // [B*T][1024]
    __shared__ __align__(16) bf16 lK[2][4096];
    __shared__ __align__(16) bf16 lP[4][32 * 36];   // [q 32][t 32+4 pad] per kf

    const int T = 2048, CQ = 3072;
    int tid = threadIdx.x, wid = tid >> 6, lane = tid & 63;
    int quad = lane >> 4, l16 = lane & 15;
    // bh spread so each XCD's 8 bh (4MB K+V) fits its L2; heavy qb first.
    int x = blockIdx.x;
    int bh = ((x & 7) << 3) | ((x >> 3) & 7);
    int qb = 15 - (x >> 6);                    // 128-row block index, 0..15
    int b = bh >> 4, h = bh & 15;
    int q0 = qb * 128;
    int rb = qb * 4 + wid;                     // this wave's 32-row block idx
    int mdiag = rb >> 1;                       // k-tile containing diagonal
    int ntiles = qb * 2 + 2;                   // tiles staged by this block

    const bf16* qbase = qkv + (size_t)(b * T + q0 + wid * 32) * CQ + h * 64;
    const bf16* kbase = qkv + (size_t)(b * T) * CQ + 1024 + h * 64;
    // per-lane V base: row l16 (d), col quad*8 (t); vb[dn] adds dn*16 rows
    const bf16* vlane = vt + ((size_t)(bh * 64 + l16)) * T + quad * 8;
    bf16* lPw = lP[wid];

    // stage K tile kt into buffer buf: [row 64][col 64] bf16, 16B chunk index
    // XOR-swizzled by row&7 on the GLOBAL side (LDS dest stays linear).
    auto stageK = [&](int kt, int buf) {
        int t0 = kt * 64;
#pragma unroll
        for (int i = 0; i < 2; ++i) {
            int j = (wid * 2 + i) * 64 + lane;         // 0..511 16B-chunk id
            int r = j >> 3;                            // row (t)
            int cs = ((j ^ r) & 7) * 8;                // swizzled col offset
            gld_lds16(kbase + (size_t)(t0 + r) * CQ + cs, &lK[buf][(wid * 2 + i) * 512]);
        }
    };

    // Q B-frags (2 row-halves of this wave's 32 rows), prescaled into exp2 domain
    const float QSCALE = 0.125f * 1.44269504088896341f;
    bf16x8 qf[2][2];
#pragma unroll
    for (int qi = 0; qi < 2; ++qi)
#pragma unroll
        for (int kf = 0; kf < 2; ++kf) {
            bf16x8 v = *(const bf16x8*)(qbase + (size_t)(qi * 16 + l16) * CQ + kf * 32 + quad * 8);
#pragma unroll
            for (int j = 0; j < 8; ++j) v[j] = (bf16)((float)v[j] * QSCALE);
            qf[qi][kf] = v;
        }

    f32x4 zero = {0.f, 0.f, 0.f, 0.f};
    f32x4 minit = {-14.4269504089f, -14.4269504089f, -14.4269504089f, -14.4269504089f};
    f32x4 o[2][4];
    f32x4 ls[2];
#pragma unroll
    for (int qi = 0; qi < 2; ++qi) {
        ls[qi] = zero;
#pragma unroll
        for (int i = 0; i < 4; ++i) o[qi][i] = zero;
    }
    bf16x8 ones;
#pragma unroll
    for (int j = 0; j < 8; ++j) ones[j] = (bf16)1.0f;

    stageK(0, 0);                              // 2 loads outstanding
    for (int kt = 0; kt < ntiles; ++kt) {
        __syncthreads();                       // K(kt) landed everywhere
        if (kt + 1 < ntiles) stageK(kt + 1, (kt + 1) & 1);  // stays in flight
        if (kt > mdiag) continue;              // no live cols; still hit barriers
        const bf16* Kb = lK[kt & 1];
        const bf16* Vt = vlane + kt * 64;
        bool diag = (kt == mdiag);
        bool half = diag && !(rb & 1);         // even rb: only t 0..31 live
        int in_hi = half ? 2 : 4;
        int khi = half ? 1 : 2;                // kf halves with live cols

        // S^T = K (Q*log2e/8)^T - 10*log2e : lane holds q=l16, t=in*16+quad*4+r
        // First MFMA takes MINIT as C directly — no per-tile acc-init movs.
        f32x4 s[2][4];
#pragma unroll
        for (int in = 0; in < 4; ++in) {
            if (in >= in_hi) break;
            bf16x8 kb0 = *(const bf16x8*)(Kb + (in * 16 + l16) * 64 + ((quad ^ (l16 & 7)) * 8));
            bf16x8 kb1 = *(const bf16x8*)(Kb + (in * 16 + l16) * 64 + (((4 + quad) ^ (l16 & 7)) * 8));
#pragma unroll
            for (int qi = 0; qi < 2; ++qi) {
                f32x4 t0 = __builtin_amdgcn_mfma_f32_16x16x32_bf16(kb0, qf[qi][0], minit, 0, 0, 0);
                s[qi][in] = __builtin_amdgcn_mfma_f32_16x16x32_bf16(kb1, qf[qi][1], t0, 0, 0, 0);
            }
        }

        // V frags kf=0 issued now — L2 latency hides behind exp + P writes
        bf16x8 vb0[4], vb1[4];
#pragma unroll
        for (int dn = 0; dn < 4; ++dn)
            vb0[dn] = *(const bf16x8*)(Vt + (size_t)(dn * 16) * T);

        int rl0 = (rb * 32) - kt * 64;         // q offset rel to tile t-base
        for (int kf = 0; kf < khi; ++kf) {
            // p = exp2(S) for this kf's 32 t-cols; causal mask on diag;
            // P -> lP[32][36] as packed b64
#pragma unroll
            for (int qi = 0; qi < 2; ++qi) {
                int qloc = rl0 + qi * 16 + l16;
#pragma unroll
                for (int in2 = 0; in2 < 2; ++in2) {
                    int in = kf * 2 + in2;
                    bf16x4 pk4;
                    if (in >= in_hi) {
                        pk4[0] = pk4[1] = pk4[2] = pk4[3] = (bf16)0.f;
                    } else {
#pragma unroll
                        for (int r = 0; r < 4; ++r) {
                            float e = __builtin_amdgcn_exp2f(s[qi][in][r]);
                            if (diag) {
                                int tloc = kf * 32 + in2 * 16 + quad * 4 + r;
                                if (tloc > qloc) e = 0.f;
                            }
                            pk4[r] = (bf16)e;
                        }
                    }
                    *(bf16x4*)(lPw + (qi * 16 + l16) * 36 + in2 * 16 + quad * 4) = pk4;
                }
            }
            if (kf == 0 && khi == 2) {
                // V frags kf=1: issued before vb0 is consumed; latency hides
                // behind kf=0's PV + kf=1's exp
#pragma unroll
                for (int dn = 0; dn < 4; ++dn)
                    vb1[dn] = *(const bf16x8*)(Vt + (size_t)(dn * 16) * T + 32);
            }
            // P A-frags (same-wave LDS), O += P V, rowsum += P*ones
#pragma unroll
            for (int qi = 0; qi < 2; ++qi) {
                bf16x8 pa = *(const bf16x8*)(lPw + (qi * 16 + l16) * 36 + quad * 8);
                ls[qi] = __builtin_amdgcn_mfma_f32_16x16x32_bf16(pa, ones, ls[qi], 0, 0, 0);
#pragma unroll
                for (int dn = 0; dn < 4; ++dn)
                    o[qi][dn] = __builtin_amdgcn_mfma_f32_16x16x32_bf16(
                        pa, kf ? vb1[dn] : vb0[dn], o[qi][dn], 0, 0, 0);
            }
        }
    }

    // epilogue: ls[qi][r] = rowsum for q=quad*4+r — exact same C-layout rows
    // as o[qi][dn][r]; no cross-lane reduction needed.
#pragma unroll
    for (int qi = 0; qi < 2; ++qi)
#pragma unroll
        for (int r = 0; r < 4; ++r) {
            float li = 1.f / ls[qi][r];
            int row = q0 + wid * 32 + qi * 16 + quad * 4 + r;
#pragma unroll
            for (int dn = 0; dn < 4; ++dn) {
                float v = o[qi][dn][r] * li;
                y[(size_t)(b * T + row) * 1024 + h * 64 + dn * 16 + l16] = (bf16)v;
            }
        }
}

extern "C" void kernel_launch(void* const* d_in, const int* in_sizes, int n_in,
                              void* d_out, int out_size, void* d_ws, size_t ws_size,
                              hipStream_t stream) {
    const float* x     = (const float*)d_in[0];
    const float* w_qkv = (const float*)d_in[1];
    const float* b_qkv = (const float*)d_in[2];
    const float* w_out = (const float*)d_in[3];
    const float* b_out = (const float*)d_in[4];
    float* out = (float*)d_out;

    const int B = 4, T = 2048, C = 1024, H = 16;
    const int M = B * T;  // 8192

    // workspace layout (88 MB total); vt aliases xb (xb dead after GEMM1)
    char* ws = (char*)d_ws;
    bf16* xb    = (bf16*)(ws);                        // 16 MB
    bf16* wqkvT = (bf16*)(ws + (16ull << 20));        //  6 MB
    bf16* woutT = (bf16*)(ws + (22ull << 20));        //  2 MB
    bf16* qkvb  = (bf16*)(ws + (24ull << 20));        // 48 MB
    bf16* yb    = (bf16*)(ws + (72ull << 20));        // 16 MB
    bf16* vtb   = xb;

    k_cvt_bf16<<<(M * C / 4 + 255) / 256, 256, 0, stream>>>(x, xb, M * C / 4);
    k_transpose_cvt<<<dim3(3 * C / 64, C / 64), 256, 0, stream>>>(w_qkv, wqkvT, C, 3 * C);
    k_transpose_cvt<<<dim3(C / 64, C / 64), 256, 0, stream>>>(w_out, woutT, C, C);
    k_gemm<true><<<dim3(3 * C / 128, M / 128), 256, 0, stream>>>(xb, wqkvT, b_qkv, qkvb, M, 3 * C, C);
    k_transpose_v<<<dim3(T / 64, B * H), 256, 0, stream>>>(qkvb, vtb);
    k_attn<<<dim3(1024, 1), 256, 0, stream>>>(qkvb, vtb, yb);
    k_gemm<false><<<dim3(C / 128, M / 128), 256, 0, stream>>>(yb, woutT, b_out, out, M, C, C);
}

// Round 11
// 258.460 us; speedup vs baseline: 1.2973x; 1.2973x over previous
//
#include <hip/hip_runtime.h>
#include <hip/hip_bf16.h>
#include <math.h>

// B=4, T=2048, C=1024, H=16, D=64. All dims divide tiles exactly.
typedef __bf16 bf16;
typedef __bf16 bf16x8 __attribute__((ext_vector_type(8)));
typedef __bf16 bf16x4 __attribute__((ext_vector_type(4)));
typedef float  f32x4  __attribute__((ext_vector_type(4)));

// async 16B/lane global->LDS. lds base must be wave-uniform; HW adds lane*16.
__device__ __forceinline__ void gld_lds16(const bf16* g, bf16* l) {
    void* gv = (void*)g;  // drop const
    __builtin_amdgcn_global_load_lds(
        (__attribute__((address_space(1))) void*)gv,
        (__attribute__((address_space(3))) void*)l, 16, 0, 0);
}

// ---------------- fp32 -> bf16 elementwise cast ----------------
__global__ void k_cvt_bf16(const float* __restrict__ in, bf16* __restrict__ out, int n4) {
    int i = blockIdx.x * blockDim.x + threadIdx.x;
    if (i < n4) {
        float4 v = ((const float4*)in)[i];
        bf16x4 o;
        o[0] = (bf16)v.x; o[1] = (bf16)v.y; o[2] = (bf16)v.z; o[3] = (bf16)v.w;
        ((bf16x4*)out)[i] = o;
    }
}

// ---------------- fp32 [R][C] -> bf16 [C][R] transpose+cast ----------------
// grid (C/64, R/64), block 256
__global__ void k_transpose_cvt(const float* __restrict__ in, bf16* __restrict__ out,
                                int R, int C) {
    __shared__ float tile[64][68];
    int c0 = blockIdx.x * 64, r0 = blockIdx.y * 64;
    int tid = threadIdx.x;
#pragma unroll
    for (int i = 0; i < 4; ++i) {            // 1024 float4 chunks
        int chunk = tid + i * 256;
        int r = chunk >> 4, c4 = (chunk & 15) * 4;
        float4 v = *(const float4*)(in + (size_t)(r0 + r) * C + c0 + c4);
        tile[r][c4 + 0] = v.x; tile[r][c4 + 1] = v.y;
        tile[r][c4 + 2] = v.z; tile[r][c4 + 3] = v.w;
    }
    __syncthreads();
#pragma unroll
    for (int i = 0; i < 2; ++i) {            // 512 chunks of 8 bf16
        int chunk = tid + i * 256;
        int c = chunk >> 3, k8 = (chunk & 7) * 8;
        bf16x8 v;
#pragma unroll
        for (int j = 0; j < 8; ++j) v[j] = (bf16)tile[k8 + j][c];
        *(bf16x8*)(out + (size_t)(c0 + c) * R + r0 + k8) = v;
    }
}

// ---------------- V slice of qkv -> vt[(bh*64+d)*2048 + t] ----------------
// grid (T/64, B*H), block 256
__global__ void k_transpose_v(const bf16* __restrict__ qkv, bf16* __restrict__ vt) {
    __shared__ bf16 tile[64][72];
    int bh = blockIdx.y, b = bh >> 4, h = bh & 15;
    int t0 = blockIdx.x * 64;
    int tid = threadIdx.x;
    const bf16* src = qkv + (size_t)(b * 2048 + t0) * 3072 + 2048 + h * 64;
#pragma unroll
    for (int i = 0; i < 2; ++i) {
        int chunk = tid + i * 256;
        int t = chunk >> 3, d8 = (chunk & 7) * 8;
        bf16x8 v = *(const bf16x8*)(src + (size_t)t * 3072 + d8);
#pragma unroll
        for (int j = 0; j < 8; ++j) tile[t][d8 + j] = v[j];
    }
    __syncthreads();
#pragma unroll
    for (int i = 0; i < 2; ++i) {
        int chunk = tid + i * 256;
        int d = chunk >> 3, t8 = (chunk & 7) * 8;
        bf16x8 v;
#pragma unroll
        for (int j = 0; j < 8; ++j) v[j] = tile[t8 + j][d];
        *(bf16x8*)(vt + ((size_t)bh * 64 + d) * 2048 + t0 + t8) = v;
    }
}

// ---------------- GEMM: C[M][N] = A[M][K] * Bt[N][K]^T + bias ----------------
// 128x128 block tile, 4 waves (2x2) of 64x64, BK=64 kf-split LDS [2][128][32]
// (bank-uniform), global_load_lds width=16 staging, mfma 16x16x32 bf16.
// (Round-8 lesson: explicit double-buffer 2-phase was neutral-to-negative —
// Common-mistake #5; implicit 2-block/CU overlap already covers the latency.)
template <bool OUT_BF16>
__global__ __launch_bounds__(256, 2) void k_gemm(
    const bf16* __restrict__ A, const bf16* __restrict__ Bt,
    const float* __restrict__ bias, void* __restrict__ Cout,
    int M, int N, int K) {
    __shared__ __align__(16) bf16 lA[2][4096];
    __shared__ __align__(16) bf16 lB[2][4096];
    int tid = threadIdx.x;
    int wid = tid >> 6, lane = tid & 63;
    int quad = lane >> 4, l16 = lane & 15;
    int bm = blockIdx.y * 128, bn = blockIdx.x * 128;
    int wm = (wid >> 1) * 64, wn = (wid & 1) * 64;

    f32x4 zero = {0.f, 0.f, 0.f, 0.f};
    f32x4 acc[4][4];
#pragma unroll
    for (int i = 0; i < 4; ++i)
#pragma unroll
        for (int j = 0; j < 4; ++j) acc[i][j] = zero;

    for (int k0 = 0; k0 < K; k0 += 64) {
        __syncthreads();
#pragma unroll
        for (int i = 0; i < 4; ++i) {
            int j = (wid * 4 + i) * 64 + lane;          // 0..1023
            int kf = j >> 9, row = (j & 511) >> 2, c8 = (j & 3) * 8;
            gld_lds16(A  + (size_t)(bm + row) * K + k0 + kf * 32 + c8, &lA[0][0] + (wid * 4 + i) * 512);
            gld_lds16(Bt + (size_t)(bn + row) * K + k0 + kf * 32 + c8, &lB[0][0] + (wid * 4 + i) * 512);
        }
        __syncthreads();
#pragma unroll
        for (int kk = 0; kk < 2; ++kk) {
            bf16x8 af[4], bg[4];
#pragma unroll
            for (int i = 0; i < 4; ++i) {
                af[i] = *(const bf16x8*)(&lA[kk][(wm + i * 16 + l16) * 32 + quad * 8]);
                bg[i] = *(const bf16x8*)(&lB[kk][(wn + i * 16 + l16) * 32 + quad * 8]);
            }
#pragma unroll
            for (int i = 0; i < 4; ++i)
#pragma unroll
                for (int j = 0; j < 4; ++j)
                    acc[i][j] = __builtin_amdgcn_mfma_f32_16x16x32_bf16(af[i], bg[j], acc[i][j], 0, 0, 0);
        }
    }
#pragma unroll
    for (int i = 0; i < 4; ++i) {
#pragma unroll
        for (int j = 0; j < 4; ++j) {
            int col = bn + wn + j * 16 + l16;
            float bv = bias ? bias[col] : 0.f;
#pragma unroll
            for (int r = 0; r < 4; ++r) {
                int row = bm + wm + i * 16 + quad * 4 + r;
                float v = acc[i][j][r] + bv;
                if (OUT_BF16) ((bf16*)Cout)[(size_t)row * N + col] = (bf16)v;
                else          ((float*)Cout)[(size_t)row * N + col] = v;
            }
        }
    }
}

// ---------------- flash attention (v14: v11 + V double-buffer) ---------------
// Base = v11 (79.8us best). v13 (V direct-from-global) failed: per-wave loads
// lose cross-wave sharing -> 4x L2 demand (FETCH 25.6->33MB, 141us). V stays
// in LDS. Delta vs v11: V is DOUBLE-buffered like K — stage(kt+1) issued right
// after the top barrier, consumed NEXT iteration, so every staged load has a
// full compute phase (~1500cy) to land instead of V's ~250cy in v11 (the
// per-iteration vmcnt(2) stall). No explicit vmcnt asm left: __syncthreads'
// vmcnt(0)+barrier drains exactly the 4 loads staged last iteration.
// LDS budget for 4 blocks/CU (40KB): lP shrunk [32][36]->[32][32] with XOR
// swizzle elem ^= ((q>>1)&3)<<3 (involution, same on write+read; b64 writes
// and b128 reads both exactly 2-way bank-aliased = free per m136).
// 16K(lK dbuf) + 16K(lV dbuf) + 8K(lP) = 40960 B exactly.
// Kept: MINIT C-operand init, exp2 domain, MFMA-ones rowsum, K XOR swizzle
// both-sides, khi skip of dead kf=1 on even-rb diag tiles (validated r10),
// heavy-qb-first static mapping (work-stealing breaks L2 locality: r7).
__global__ __launch_bounds__(256, 4) void k_attn(
    const bf16* __restrict__ qkv,   // [B*T][3072]
    const bf16* __restrict__ vt,    // [(bh*64+d)*2048 + t]
    bf16* __restrict__ y) {         // [B*T][1024]
    __shared__ __align__(16) bf16 lK[2][4096];
    __shared__ __align__(16) bf16 lV[2][4096];
    __shared__ __align__(16) bf16 lP[4][1024];   // [q 32][t 32] swizzled

    const int T = 2048, CQ = 3072;
    int tid = threadIdx.x, wid = tid >> 6, lane = tid & 63;
    int quad = lane >> 4, l16 = lane & 15;
    // bh spread so each XCD's 8 bh (4MB K+V) fits its L2; heavy qb first.
    int x = blockIdx.x;
    int bh = ((x & 7) << 3) | ((x >> 3) & 7);
    int qb = 15 - (x >> 6);                    // 128-row block index, 0..15
    int b = bh >> 4, h = bh & 15;
    int q0 = qb * 128;
    int rb = qb * 4 + wid;                     // this wave's 32-row block idx
    int mdiag = rb >> 1;                       // k-tile containing diagonal
    int ntiles = qb * 2 + 2;                   // tiles staged by this block

    const bf16* qbase = qkv + (size_t)(b * T + q0 + wid * 32) * CQ + h * 64;
    const bf16* kbase = qkv + (size_t)(b * T) * CQ + 1024 + h * 64;
    const bf16* vbase = vt + (size_t)bh * 64 * T;
    bf16* lPw = lP[wid];
    int sE = ((l16 >> 1) & 3) * 8;             // lP swizzle (elements), row=l16

    // stage K/V tile kt into buffer buf: [row 64][col 64] bf16, 16B chunk
    // index XOR-swizzled by row&7 on the GLOBAL side (LDS dest stays linear).
    auto stageK = [&](int kt, int buf) {
        int t0 = kt * 64;
#pragma unroll
        for (int i = 0; i < 2; ++i) {
            int j = (wid * 2 + i) * 64 + lane;         // 0..511 16B-chunk id
            int r = j >> 3;                            // row (t)
            int cs = ((j ^ r) & 7) * 8;                // swizzled col offset
            gld_lds16(kbase + (size_t)(t0 + r) * CQ + cs, &lK[buf][(wid * 2 + i) * 512]);
        }
    };
    auto stageV = [&](int kt, int buf) {
        int t0 = kt * 64;
#pragma unroll
        for (int i = 0; i < 2; ++i) {
            int j = (wid * 2 + i) * 64 + lane;
            int r = j >> 3;                            // row (d)
            int cs = ((j ^ r) & 7) * 8;
            gld_lds16(vbase + (size_t)r * T + t0 + cs, &lV[buf][(wid * 2 + i) * 512]);
        }
    };

    // Q B-frags (2 row-halves of this wave's 32 rows), prescaled into exp2 domain
    const float QSCALE = 0.125f * 1.44269504088896341f;
    bf16x8 qf[2][2];
#pragma unroll
    for (int qi = 0; qi < 2; ++qi)
#pragma unroll
        for (int kf = 0; kf < 2; ++kf) {
            bf16x8 v = *(const bf16x8*)(qbase + (size_t)(qi * 16 + l16) * CQ + kf * 32 + quad * 8);
#pragma unroll
            for (int j = 0; j < 8; ++j) v[j] = (bf16)((float)v[j] * QSCALE);
            qf[qi][kf] = v;
        }

    f32x4 zero = {0.f, 0.f, 0.f, 0.f};
    f32x4 minit = {-14.4269504089f, -14.4269504089f, -14.4269504089f, -14.4269504089f};
    f32x4 o[2][4];
    f32x4 ls[2];
#pragma unroll
    for (int qi = 0; qi < 2; ++qi) {
        ls[qi] = zero;
#pragma unroll
        for (int i = 0; i < 4; ++i) o[qi][i] = zero;
    }
    bf16x8 ones;
#pragma unroll
    for (int j = 0; j < 8; ++j) ones[j] = (bf16)1.0f;

    stageK(0, 0);
    stageV(0, 0);                              // 4 loads outstanding
    for (int kt = 0; kt < ntiles; ++kt) {
        __syncthreads();                       // drains stage(kt) (4 loads,
                                               // issued a full iter ago);
                                               // buf[kt^1] readers all done
        if (kt + 1 < ntiles) {
            stageV(kt + 1, (kt + 1) & 1);      // consumed NEXT iteration —
            stageK(kt + 1, (kt + 1) & 1);      // full compute phase to land
        }
        if (kt > mdiag) continue;              // no live cols; still hit barriers
        const bf16* Kb = lK[kt & 1];
        const bf16* Vb = lV[kt & 1];
        bool diag = (kt == mdiag);
        bool half = diag && !(rb & 1);         // even rb: only t 0..31 live
        int in_hi = half ? 2 : 4;
        int khi = half ? 1 : 2;                // kf halves with live cols

        // S^T = K (Q*log2e/8)^T - 10*log2e : lane holds q=l16, t=in*16+quad*4+r
        // First MFMA takes MINIT as C directly — no per-tile acc-init movs.
        f32x4 s[2][4];
#pragma unroll
        for (int in = 0; in < 4; ++in) {
            if (in >= in_hi) break;
            bf16x8 kb0 = *(const bf16x8*)(Kb + (in * 16 + l16) * 64 + ((quad ^ (l16 & 7)) * 8));
            bf16x8 kb1 = *(const bf16x8*)(Kb + (in * 16 + l16) * 64 + (((4 + quad) ^ (l16 & 7)) * 8));
#pragma unroll
            for (int qi = 0; qi < 2; ++qi) {
                f32x4 t0 = __builtin_amdgcn_mfma_f32_16x16x32_bf16(kb0, qf[qi][0], minit, 0, 0, 0);
                s[qi][in] = __builtin_amdgcn_mfma_f32_16x16x32_bf16(kb1, qf[qi][1], t0, 0, 0, 0);
            }
        }

        int rl0 = (rb * 32) - kt * 64;         // q offset rel to tile t-base
        for (int kf = 0; kf < khi; ++kf) {
            // p = exp2(S) for this kf's 32 t-cols; causal mask on diag;
            // P -> lP[32][32] swizzled, packed b64 writes
#pragma unroll
            for (int qi = 0; qi < 2; ++qi) {
                int qloc = rl0 + qi * 16 + l16;
#pragma unroll
                for (int in2 = 0; in2 < 2; ++in2) {
                    int in = kf * 2 + in2;
                    bf16x4 pk4;
                    if (in >= in_hi) {
                        pk4[0] = pk4[1] = pk4[2] = pk4[3] = (bf16)0.f;
                    } else {
#pragma unroll
                        for (int r = 0; r < 4; ++r) {
                            float e = __builtin_amdgcn_exp2f(s[qi][in][r]);
                            if (diag) {
                                int tloc = kf * 32 + in2 * 16 + quad * 4 + r;
                                if (tloc > qloc) e = 0.f;
                            }
                            pk4[r] = (bf16)e;
                        }
                    }
                    *(bf16x4*)(lPw + (qi * 16 + l16) * 32 + ((in2 * 16 + quad * 4) ^ sE)) = pk4;
                }
            }
            // V B-frags for this kf (swizzled reads from dbuf — data landed)
            bf16x8 vb[4];
#pragma unroll
            for (int dn = 0; dn < 4; ++dn)
                vb[dn] = *(const bf16x8*)(Vb + (dn * 16 + l16) * 64 + (((kf * 4 + quad) ^ (l16 & 7)) * 8));
            // P A-frags (same-wave LDS), O += P V, rowsum += P*ones
#pragma unroll
            for (int qi = 0; qi < 2; ++qi) {
                bf16x8 pa = *(const bf16x8*)(lPw + (qi * 16 + l16) * 32 + ((quad * 8) ^ sE));
                ls[qi] = __builtin_amdgcn_mfma_f32_16x16x32_bf16(pa, ones, ls[qi], 0, 0, 0);
#pragma unroll
                for (int dn = 0; dn < 4; ++dn)
                    o[qi][dn] = __builtin_amdgcn_mfma_f32_16x16x32_bf16(pa, vb[dn], o[qi][dn], 0, 0, 0);
            }
        }
    }

    // epilogue: ls[qi][r] = rowsum for q=quad*4+r — exact same C-layout rows
    // as o[qi][dn][r]; no cross-lane reduction needed.
#pragma unroll
    for (int qi = 0; qi < 2; ++qi)
#pragma unroll
        for (int r = 0; r < 4; ++r) {
            float li = 1.f / ls[qi][r];
            int row = q0 + wid * 32 + qi * 16 + quad * 4 + r;
#pragma unroll
            for (int dn = 0; dn < 4; ++dn) {
                float v = o[qi][dn][r] * li;
                y[(size_t)(b * T + row) * 1024 + h * 64 + dn * 16 + l16] = (bf16)v;
            }
        }
}

extern "C" void kernel_launch(void* const* d_in, const int* in_sizes, int n_in,
                              void* d_out, int out_size, void* d_ws, size_t ws_size,
                              hipStream_t stream) {
    const float* x     = (const float*)d_in[0];
    const float* w_qkv = (const float*)d_in[1];
    const float* b_qkv = (const float*)d_in[2];
    const float* w_out = (const float*)d_in[3];
    const float* b_out = (const float*)d_in[4];
    float* out = (float*)d_out;

    const int B = 4, T = 2048, C = 1024, H = 16;
    const int M = B * T;  // 8192

    // workspace layout (88 MB total); vt aliases xb (xb dead after GEMM1)
    char* ws = (char*)d_ws;
    bf16* xb    = (bf16*)(ws);                        // 16 MB
    bf16* wqkvT = (bf16*)(ws + (16ull << 20));        //  6 MB
    bf16* woutT = (bf16*)(ws + (22ull << 20));        //  2 MB
    bf16* qkvb  = (bf16*)(ws + (24ull << 20));        // 48 MB
    bf16* yb    = (bf16*)(ws + (72ull << 20));        // 16 MB
    bf16* vtb   = xb;

    k_cvt_bf16<<<(M * C / 4 + 255) / 256, 256, 0, stream>>>(x, xb, M * C / 4);
    k_transpose_cvt<<<dim3(3 * C / 64, C / 64), 256, 0, stream>>>(w_qkv, wqkvT, C, 3 * C);
    k_transpose_cvt<<<dim3(C / 64, C / 64), 256, 0, stream>>>(w_out, woutT, C, C);
    k_gemm<true><<<dim3(3 * C / 128, M / 128), 256, 0, stream>>>(xb, wqkvT, b_qkv, qkvb, M, 3 * C, C);
    k_transpose_v<<<dim3(T / 64, B * H), 256, 0, stream>>>(qkvb, vtb);
    k_attn<<<dim3(1024, 1), 256, 0, stream>>>(qkvb, vtb, yb);
    k_gemm<false><<<dim3(C / 128, M / 128), 256, 0, stream>>>(yb, woutT, b_out, out, M, C, C);
}

// Round 13
// 250.673 us; speedup vs baseline: 1.3376x; 1.0311x over previous
//
#include <hip/hip_runtime.h>
#include <hip/hip_bf16.h>
#include <math.h>

// B=4, T=2048, C=1024, H=16, D=64. All dims divide tiles exactly.
typedef __bf16 bf16;
typedef __bf16 bf16x8 __attribute__((ext_vector_type(8)));
typedef __bf16 bf16x4 __attribute__((ext_vector_type(4)));
typedef float  f32x4  __attribute__((ext_vector_type(4)));

// async 16B/lane global->LDS. lds base must be wave-uniform; HW adds lane*16.
__device__ __forceinline__ void gld_lds16(const bf16* g, bf16* l) {
    void* gv = (void*)g;  // drop const
    __builtin_amdgcn_global_load_lds(
        (__attribute__((address_space(1))) void*)gv,
        (__attribute__((address_space(3))) void*)l, 16, 0, 0);
}

// ---------------- fp32 -> bf16 elementwise cast ----------------
__global__ void k_cvt_bf16(const float* __restrict__ in, bf16* __restrict__ out, int n4) {
    int i = blockIdx.x * blockDim.x + threadIdx.x;
    if (i < n4) {
        float4 v = ((const float4*)in)[i];
        bf16x4 o;
        o[0] = (bf16)v.x; o[1] = (bf16)v.y; o[2] = (bf16)v.z; o[3] = (bf16)v.w;
        ((bf16x4*)out)[i] = o;
    }
}

// ---------------- fp32 [R][C] -> bf16 [C][R] transpose+cast ----------------
// grid (C/64, R/64), block 256
__global__ void k_transpose_cvt(const float* __restrict__ in, bf16* __restrict__ out,
                                int R, int C) {
    __shared__ float tile[64][68];
    int c0 = blockIdx.x * 64, r0 = blockIdx.y * 64;
    int tid = threadIdx.x;
#pragma unroll
    for (int i = 0; i < 4; ++i) {            // 1024 float4 chunks
        int chunk = tid + i * 256;
        int r = chunk >> 4, c4 = (chunk & 15) * 4;
        float4 v = *(const float4*)(in + (size_t)(r0 + r) * C + c0 + c4);
        tile[r][c4 + 0] = v.x; tile[r][c4 + 1] = v.y;
        tile[r][c4 + 2] = v.z; tile[r][c4 + 3] = v.w;
    }
    __syncthreads();
#pragma unroll
    for (int i = 0; i < 2; ++i) {            // 512 chunks of 8 bf16
        int chunk = tid + i * 256;
        int c = chunk >> 3, k8 = (chunk & 7) * 8;
        bf16x8 v;
#pragma unroll
        for (int j = 0; j < 8; ++j) v[j] = (bf16)tile[k8 + j][c];
        *(bf16x8*)(out + (size_t)(c0 + c) * R + r0 + k8) = v;
    }
}

// ---------------- V slice of qkv -> vt[(bh*64+d)*2048 + t] ----------------
// grid (T/64, B*H), block 256
__global__ void k_transpose_v(const bf16* __restrict__ qkv, bf16* __restrict__ vt) {
    __shared__ bf16 tile[64][72];
    int bh = blockIdx.y, b = bh >> 4, h = bh & 15;
    int t0 = blockIdx.x * 64;
    int tid = threadIdx.x;
    const bf16* src = qkv + (size_t)(b * 2048 + t0) * 3072 + 2048 + h * 64;
#pragma unroll
    for (int i = 0; i < 2; ++i) {
        int chunk = tid + i * 256;
        int t = chunk >> 3, d8 = (chunk & 7) * 8;
        bf16x8 v = *(const bf16x8*)(src + (size_t)t * 3072 + d8);
#pragma unroll
        for (int j = 0; j < 8; ++j) tile[t][d8 + j] = v[j];
    }
    __syncthreads();
#pragma unroll
    for (int i = 0; i < 2; ++i) {
        int chunk = tid + i * 256;
        int d = chunk >> 3, t8 = (chunk & 7) * 8;
        bf16x8 v;
#pragma unroll
        for (int j = 0; j < 8; ++j) v[j] = tile[t8 + j][d];
        *(bf16x8*)(vt + ((size_t)bh * 64 + d) * 2048 + t0 + t8) = v;
    }
}

// ---------------- GEMM: C[M][N] = A[M][K] * Bt[N][K]^T + bias ----------------
// 128x128 block tile, 4 waves (2x2) of 64x64, BK=64, mfma 16x16x32 bf16.
// v3: XOR-swizzled LDS [128 rows][64 cols] (was [kf][128][32]). Bank audit of
// the old layout: af[i] read at byte row*64+quad*16, bank=(row*16+quad*4)%32;
// 16 lanes with row=..+l16 alternate {0,16} -> 8 lanes per 4-bank group =
// 8-WAY CONFLICT (2.94x, m136) on all 16 b128 frag reads per K-step — the
// same conflict attn's K-reads had before r4's fix. New layout stores 16B
// chunk slot (j&7) = global chunk ((j&7)^(r&7)) via pre-swizzled global
// source (LDS dest linear, rule #21); frags read chunk (kk*4+quad)^(l16&7):
// banks spread to 8 groups x 2 lanes = free. Same data, same LDS size (32KB),
// same 1-phase loop (r8: explicit dbuf neutral — Common-mistake #5).
template <bool OUT_BF16>
__global__ __launch_bounds__(256, 2) void k_gemm(
    const bf16* __restrict__ A, const bf16* __restrict__ Bt,
    const float* __restrict__ bias, void* __restrict__ Cout,
    int M, int N, int K) {
    __shared__ __align__(16) bf16 lA[8192];   // [row 128][col 64] swizzled
    __shared__ __align__(16) bf16 lB[8192];
    int tid = threadIdx.x;
    int wid = tid >> 6, lane = tid & 63;
    int quad = lane >> 4, l16 = lane & 15;
    int bm = blockIdx.y * 128, bn = blockIdx.x * 128;
    int wm = (wid >> 1) * 64, wn = (wid & 1) * 64;

    f32x4 zero = {0.f, 0.f, 0.f, 0.f};
    f32x4 acc[4][4];
#pragma unroll
    for (int i = 0; i < 4; ++i)
#pragma unroll
        for (int j = 0; j < 4; ++j) acc[i][j] = zero;

    for (int k0 = 0; k0 < K; k0 += 64) {
        __syncthreads();
#pragma unroll
        for (int i = 0; i < 4; ++i) {
            int j = (wid * 4 + i) * 64 + lane;          // 0..1023 16B-chunk id
            int r = j >> 3;                             // row 0..127
            int cs = ((j ^ r) & 7) * 8;                 // swizzled col (elems)
            gld_lds16(A  + (size_t)(bm + r) * K + k0 + cs, &lA[0] + (wid * 4 + i) * 512);
            gld_lds16(Bt + (size_t)(bn + r) * K + k0 + cs, &lB[0] + (wid * 4 + i) * 512);
        }
        __syncthreads();
#pragma unroll
        for (int kk = 0; kk < 2; ++kk) {
            bf16x8 af[4], bg[4];
#pragma unroll
            for (int i = 0; i < 4; ++i) {
                int ra = wm + i * 16 + l16;            // ra&7 == l16&7
                int rb = wn + i * 16 + l16;
                af[i] = *(const bf16x8*)(&lA[ra * 64 + (((kk * 4 + quad) ^ (l16 & 7)) * 8)]);
                bg[i] = *(const bf16x8*)(&lB[rb * 64 + (((kk * 4 + quad) ^ (l16 & 7)) * 8)]);
            }
#pragma unroll
            for (int i = 0; i < 4; ++i)
#pragma unroll
                for (int j = 0; j < 4; ++j)
                    acc[i][j] = __builtin_amdgcn_mfma_f32_16x16x32_bf16(af[i], bg[j], acc[i][j], 0, 0, 0);
        }
    }
#pragma unroll
    for (int i = 0; i < 4; ++i) {
#pragma unroll
        for (int j = 0; j < 4; ++j) {
            int col = bn + wn + j * 16 + l16;
            float bv = bias ? bias[col] : 0.f;
#pragma unroll
            for (int r = 0; r < 4; ++r) {
                int row = bm + wm + i * 16 + quad * 4 + r;
                float v = acc[i][j][r] + bv;
                if (OUT_BF16) ((bf16*)Cout)[(size_t)row * N + col] = (bf16)v;
                else          ((float*)Cout)[(size_t)row * N + col] = v;
            }
        }
    }
}

// ---------------- flash attention (v14, frozen: best measured 63.5us) --------
// V double-buffered like K (stage kt+1 post-barrier, consume next iter: full
// compute phase to land; no explicit vmcnt). lP [32][32] XOR-swizzled
// (elem ^= ((q>>1)&3)<<3; 2-way residual = free). MINIT C-operand init,
// exp2 domain, MFMA-ones rowsum, K/V XOR swizzle both-sides, khi skip on
// even-rb diag tiles, heavy-qb-first static mapping (stealing breaks L2: r7;
// V direct-from-global breaks cross-wave sharing: r10).
__global__ __launch_bounds__(256, 4) void k_attn(
    const bf16* __restrict__ qkv,   // [B*T][3072]
    const bf16* __restrict__ vt,    // [(bh*64+d)*2048 + t]
    bf16* __restrict__ y) {         // [B*T][1024]
    __shared__ __align__(16) bf16 lK[2][4096];
    __shared__ __align__(16) bf16 lV[2][4096];
    __shared__ __align__(16) bf16 lP[4][1024];   // [q 32][t 32] swizzled

    const int T = 2048, CQ = 3072;
    int tid = threadIdx.x, wid = tid >> 6, lane = tid & 63;
    int quad = lane >> 4, l16 = lane & 15;
    // bh spread so each XCD's 8 bh (4MB K+V) fits its L2; heavy qb first.
    int x = blockIdx.x;
    int bh = ((x & 7) << 3) | ((x >> 3) & 7);
    int qb = 15 - (x >> 6);                    // 128-row block index, 0..15
    int b = bh >> 4, h = bh & 15;
    int q0 = qb * 128;
    int rb = qb * 4 + wid;                     // this wave's 32-row block idx
    int mdiag = rb >> 1;                       // k-tile containing diagonal
    int ntiles = qb * 2 + 2;                   // tiles staged by this block

    const bf16* qbase = qkv + (size_t)(b * T + q0 + wid * 32) * CQ + h * 64;
    const bf16* kbase = qkv + (size_t)(b * T) * CQ + 1024 + h * 64;
    const bf16* vbase = vt + (size_t)bh * 64 * T;
    bf16* lPw = lP[wid];
    int sE = ((l16 >> 1) & 3) * 8;             // lP swizzle (elements), row=l16

    // stage K/V tile kt into buffer buf: [row 64][col 64] bf16, 16B chunk
    // index XOR-swizzled by row&7 on the GLOBAL side (LDS dest stays linear).
    auto stageK = [&](int kt, int buf) {
        int t0 = kt * 64;
#pragma unroll
        for (int i = 0; i < 2; ++i) {
            int j = (wid * 2 + i) * 64 + lane;         // 0..511 16B-chunk id
            int r = j >> 3;                            // row (t)
            int cs = ((j ^ r) & 7) * 8;                // swizzled col offset
            gld_lds16(kbase + (size_t)(t0 + r) * CQ + cs, &lK[buf][(wid * 2 + i) * 512]);
        }
    };
    auto stageV = [&](int kt, int buf) {
        int t0 = kt * 64;
#pragma unroll
        for (int i = 0; i < 2; ++i) {
            int j = (wid * 2 + i) * 64 + lane;
            int r = j >> 3;                            // row (d)
            int cs = ((j ^ r) & 7) * 8;
            gld_lds16(vbase + (size_t)r * T + t0 + cs, &lV[buf][(wid * 2 + i) * 512]);
        }
    };

    // Q B-frags (2 row-halves of this wave's 32 rows), prescaled into exp2 domain
    const float QSCALE = 0.125f * 1.44269504088896341f;
    bf16x8 qf[2][2];
#pragma unroll
    for (int qi = 0; qi < 2; ++qi)
#pragma unroll
        for (int kf = 0; kf < 2; ++kf) {
            bf16x8 v = *(const bf16x8*)(qbase + (size_t)(qi * 16 + l16) * CQ + kf * 32 + quad * 8);
#pragma unroll
            for (int j = 0; j < 8; ++j) v[j] = (bf16)((float)v[j] * QSCALE);
            qf[qi][kf] = v;
        }

    f32x4 zero = {0.f, 0.f, 0.f, 0.f};
    f32x4 minit = {-14.4269504089f, -14.4269504089f, -14.4269504089f, -14.4269504089f};
    f32x4 o[2][4];
    f32x4 ls[2];
#pragma unroll
    for (int qi = 0; qi < 2; ++qi) {
        ls[qi] = zero;
#pragma unroll
        for (int i = 0; i < 4; ++i) o[qi][i] = zero;
    }
    bf16x8 ones;
#pragma unroll
    for (int j = 0; j < 8; ++j) ones[j] = (bf16)1.0f;

    stageK(0, 0);
    stageV(0, 0);                              // 4 loads outstanding
    for (int kt = 0; kt < ntiles; ++kt) {
        __syncthreads();                       // drains stage(kt) (4 loads,
                                               // issued a full iter ago);
                                               // buf[kt^1] readers all done
        if (kt + 1 < ntiles) {
            stageV(kt + 1, (kt + 1) & 1);      // consumed NEXT iteration —
            stageK(kt + 1, (kt + 1) & 1);      // full compute phase to land
        }
        if (kt > mdiag) continue;              // no live cols; still hit barriers
        const bf16* Kb = lK[kt & 1];
        const bf16* Vb = lV[kt & 1];
        bool diag = (kt == mdiag);
        bool half = diag && !(rb & 1);         // even rb: only t 0..31 live
        int in_hi = half ? 2 : 4;
        int khi = half ? 1 : 2;                // kf halves with live cols

        // S^T = K (Q*log2e/8)^T - 10*log2e : lane holds q=l16, t=in*16+quad*4+r
        // First MFMA takes MINIT as C directly — no per-tile acc-init movs.
        f32x4 s[2][4];
#pragma unroll
        for (int in = 0; in < 4; ++in) {
            if (in >= in_hi) break;
            bf16x8 kb0 = *(const bf16x8*)(Kb + (in * 16 + l16) * 64 + ((quad ^ (l16 & 7)) * 8));
            bf16x8 kb1 = *(const bf16x8*)(Kb + (in * 16 + l16) * 64 + (((4 + quad) ^ (l16 & 7)) * 8));
#pragma unroll
            for (int qi = 0; qi < 2; ++qi) {
                f32x4 t0 = __builtin_amdgcn_mfma_f32_16x16x32_bf16(kb0, qf[qi][0], minit, 0, 0, 0);
                s[qi][in] = __builtin_amdgcn_mfma_f32_16x16x32_bf16(kb1, qf[qi][1], t0, 0, 0, 0);
            }
        }

        int rl0 = (rb * 32) - kt * 64;         // q offset rel to tile t-base
        for (int kf = 0; kf < khi; ++kf) {
            // p = exp2(S) for this kf's 32 t-cols; causal mask on diag;
            // P -> lP[32][32] swizzled, packed b64 writes
#pragma unroll
            for (int qi = 0; qi < 2; ++qi) {
                int qloc = rl0 + qi * 16 + l16;
#pragma unroll
                for (int in2 = 0; in2 < 2; ++in2) {
                    int in = kf * 2 + in2;
                    bf16x4 pk4;
                    if (in >= in_hi) {
                        pk4[0] = pk4[1] = pk4[2] = pk4[3] = (bf16)0.f;
                    } else {
#pragma unroll
                        for (int r = 0; r < 4; ++r) {
                            float e = __builtin_amdgcn_exp2f(s[qi][in][r]);
                            if (diag) {
                                int tloc = kf * 32 + in2 * 16 + quad * 4 + r;
                                if (tloc > qloc) e = 0.f;
                            }
                            pk4[r] = (bf16)e;
                        }
                    }
                    *(bf16x4*)(lPw + (qi * 16 + l16) * 32 + ((in2 * 16 + quad * 4) ^ sE)) = pk4;
                }
            }
            // V B-frags for this kf (swizzled reads from dbuf — data landed)
            bf16x8 vb[4];
#pragma unroll
            for (int dn = 0; dn < 4; ++dn)
                vb[dn] = *(const bf16x8*)(Vb + (dn * 16 + l16) * 64 + (((kf * 4 + quad) ^ (l16 & 7)) * 8));
            // P A-frags (same-wave LDS), O += P V, rowsum += P*ones
#pragma unroll
            for (int qi = 0; qi < 2; ++qi) {
                bf16x8 pa = *(const bf16x8*)(lPw + (qi * 16 + l16) * 32 + ((quad * 8) ^ sE));
                ls[qi] = __builtin_amdgcn_mfma_f32_16x16x32_bf16(pa, ones, ls[qi], 0, 0, 0);
#pragma unroll
                for (int dn = 0; dn < 4; ++dn)
                    o[qi][dn] = __builtin_amdgcn_mfma_f32_16x16x32_bf16(pa, vb[dn], o[qi][dn], 0, 0, 0);
            }
        }
    }

    // epilogue: ls[qi][r] = rowsum for q=quad*4+r — exact same C-layout rows
    // as o[qi][dn][r]; no cross-lane reduction needed.
#pragma unroll
    for (int qi = 0; qi < 2; ++qi)
#pragma unroll
        for (int r = 0; r < 4; ++r) {
            float li = 1.f / ls[qi][r];
            int row = q0 + wid * 32 + qi * 16 + quad * 4 + r;
#pragma unroll
            for (int dn = 0; dn < 4; ++dn) {
                float v = o[qi][dn][r] * li;
                y[(size_t)(b * T + row) * 1024 + h * 64 + dn * 16 + l16] = (bf16)v;
            }
        }
}

extern "C" void kernel_launch(void* const* d_in, const int* in_sizes, int n_in,
                              void* d_out, int out_size, void* d_ws, size_t ws_size,
                              hipStream_t stream) {
    const float* x     = (const float*)d_in[0];
    const float* w_qkv = (const float*)d_in[1];
    const float* b_qkv = (const float*)d_in[2];
    const float* w_out = (const float*)d_in[3];
    const float* b_out = (const float*)d_in[4];
    float* out = (float*)d_out;

    const int B = 4, T = 2048, C = 1024, H = 16;
    const int M = B * T;  // 8192

    // workspace layout (88 MB total); vt aliases xb (xb dead after GEMM1)
    char* ws = (char*)d_ws;
    bf16* xb    = (bf16*)(ws);                        // 16 MB
    bf16* wqkvT = (bf16*)(ws + (16ull << 20));        //  6 MB
    bf16* woutT = (bf16*)(ws + (22ull << 20));        //  2 MB
    bf16* qkvb  = (bf16*)(ws + (24ull << 20));        // 48 MB
    bf16* yb    = (bf16*)(ws + (72ull << 20));        // 16 MB
    bf16* vtb   = xb;

    k_cvt_bf16<<<(M * C / 4 + 255) / 256, 256, 0, stream>>>(x, xb, M * C / 4);
    k_transpose_cvt<<<dim3(3 * C / 64, C / 64), 256, 0, stream>>>(w_qkv, wqkvT, C, 3 * C);
    k_transpose_cvt<<<dim3(C / 64, C / 64), 256, 0, stream>>>(w_out, woutT, C, C);
    k_gemm<true><<<dim3(3 * C / 128, M / 128), 256, 0, stream>>>(xb, wqkvT, b_qkv, qkvb, M, 3 * C, C);
    k_transpose_v<<<dim3(T / 64, B * H), 256, 0, stream>>>(qkvb, vtb);
    k_attn<<<dim3(1024, 1), 256, 0, stream>>>(qkvb, vtb, yb);
    k_gemm<false><<<dim3(C / 128, M / 128), 256, 0, stream>>>(yb, woutT, b_out, out, M, C, C);
}